// Round 6
// baseline (451.887 us; speedup 1.0000x reference)
//
#include <hip/hip_runtime.h>
#include <hip/hip_bf16.h>

#define N_   4
#define CIN  1024
#define H_   56
#define W_   56
#define HW   3136
#define CB   256
#define KK   9
#define OFFC 18
#define PTOT (N_ * HW)   // 12544

typedef __attribute__((ext_vector_type(8))) short short8;
typedef __attribute__((ext_vector_type(4))) short short4v;
typedef __attribute__((ext_vector_type(4))) float float4v;
typedef __attribute__((ext_vector_type(4))) unsigned int uint4v;
typedef unsigned short ushort_t;

// fp32 -> bf16 round-to-nearest-even
__device__ inline ushort_t bf16_rne(float f) {
    unsigned int u = __float_as_uint(f);
    unsigned int r = (u + 0x7FFFu + ((u >> 16) & 1u)) >> 16;
    return (ushort_t)r;
}
__device__ inline short8 ld_frag_lds(const ushort_t* base) {
    short4v a = *(const short4v*)base;
    short4v b = *(const short4v*)(base + 4);
    return __builtin_shufflevector(a, b, 0, 1, 2, 3, 4, 5, 6, 7);
}

// ---------------------------------------------------------------------------
// Pack weights, single-plane bf16.
// w1 [256][1024]     -> w1p [o][1024]          (row-major, k contiguous)
// w2 [256][256][9]   -> w2b [o][K=2304], K = tap*256 + c
// w3 [1024][256]     -> w3p [o][256]
// w_off [18][256][9] -> wofp [tap][32][256]    (m padded 18->32 with zeros)
// ---------------------------------------------------------------------------
__global__ void __launch_bounds__(256) pack_weights_kernel(
    const float* __restrict__ w1, const float* __restrict__ w2,
    const float* __restrict__ w3, const float* __restrict__ w_off,
    ushort_t* __restrict__ w1p, ushort_t* __restrict__ w2b,
    ushort_t* __restrict__ w3p, ushort_t* __restrict__ wofp)
{
    int e = blockIdx.x * 256 + threadIdx.x;
    if (e < 256 * 1024) { w1p[e] = bf16_rne(w1[e]); return; }
    e -= 256 * 1024;
    if (e < 256 * 2304) {
        int o = e / 2304, K = e % 2304;
        int kk = K >> 8, c = K & 255;
        w2b[e] = bf16_rne(w2[(o * 256 + c) * 9 + kk]);
        return;
    }
    e -= 256 * 2304;
    if (e < 1024 * 256) { w3p[e] = bf16_rne(w3[e]); return; }
    e -= 1024 * 256;
    if (e < 9 * 32 * 256) {
        int kk = e / (32 * 256);
        int rem = e % (32 * 256);
        int m = rem >> 8, c = rem & 255;
        wofp[e] = (m < OFFC) ? bf16_rne(w_off[((size_t)m * 256 + c) * 9 + kk])
                             : (ushort_t)0;
    }
}

// ---------------------------------------------------------------------------
// conv1: r_t[p][m] = relu(b1[m] + sum_k x[n][k][p] w1[m][k]), NHWC bf16 out.
// M-dim = positions (A staged via LDS transpose), N-dim = out-channels.
// Block 256 thr = 4 waves; p-tile 64 (wave: 16 p), N = 128 (m-half in grid.y).
// ---------------------------------------------------------------------------
__global__ void __launch_bounds__(256, 4) conv1_kernel(
    const float* __restrict__ x, const ushort_t* __restrict__ w1p,
    const float* __restrict__ b1, ushort_t* __restrict__ rt)
{
    __shared__ ushort_t As[64][36];   // [p][k], pad 36

    const int tid  = threadIdx.x;
    const int wave = tid >> 6;
    const int lane = tid & 63;
    const int l15  = lane & 15;
    const int quad = lane >> 4;
    const int pBase = blockIdx.x * 64;       // global position
    const int n     = pBase / HW;
    const int p_in  = pBase % HW;
    const int mBase = blockIdx.y * 128;
    const float* Xn = x + (size_t)n * CIN * HW;

    float4v acc[8];
#pragma unroll
    for (int j = 0; j < 8; ++j) acc[j] = (float4v)(0.f);

    const int kk = tid >> 3;          // 0..31
    const int pq = (tid & 7) * 8;     // 0..56

    for (int k0 = 0; k0 < CIN; k0 += 32) {
        const float* src = &Xn[(size_t)(k0 + kk) * HW + p_in + pq];
        float4 v0 = *reinterpret_cast<const float4*>(src);
        float4 v1 = *reinterpret_cast<const float4*>(src + 4);
        __syncthreads();
        float vs[8] = {v0.x, v0.y, v0.z, v0.w, v1.x, v1.y, v1.z, v1.w};
#pragma unroll
        for (int j = 0; j < 8; ++j) As[pq + j][kk] = bf16_rne(vs[j]);
        __syncthreads();

        short8 af = ld_frag_lds(&As[wave * 16 + l15][quad * 8]);
#pragma unroll
        for (int nt = 0; nt < 8; ++nt) {
            short8 bf = *(const short8*)&w1p[(size_t)(mBase + nt * 16 + l15) * 1024 +
                                             k0 + quad * 8];
            acc[nt] = __builtin_amdgcn_mfma_f32_16x16x32_bf16(af, bf, acc[nt], 0, 0, 0);
        }
    }

#pragma unroll
    for (int rr = 0; rr < 4; ++rr) {
        int p_row = pBase + wave * 16 + quad * 4 + rr;
#pragma unroll
        for (int nt = 0; nt < 8; ++nt) {
            int m = mBase + nt * 16 + l15;
            float v = fmaxf(acc[nt][rr] + b1[m], 0.f);
            rt[(size_t)p_row * 256 + m] = bf16_rne(v);
        }
    }
}

// ---------------------------------------------------------------------------
// offset conv 3x3 SAME: off[n][18][p], global-fed MFMA, no LDS, no barriers.
// A = wofp (rows=m), B = r_t neighbor rows (cols=p). Block 128 thr = 2 waves;
// wave p-tile 16. Grid (56 h, 2 p-half, 4 n).
// ---------------------------------------------------------------------------
__global__ void __launch_bounds__(128, 4) offset_kernel(
    const ushort_t* __restrict__ rt, const ushort_t* __restrict__ wofp,
    const float* __restrict__ b_off, float* __restrict__ off)
{
    const int tid  = threadIdx.x;
    const int wave = tid >> 6;
    const int lane = tid & 63;
    const int l15  = lane & 15;
    const int quad = lane >> 4;
    const int h    = blockIdx.x;
    const int n    = blockIdx.z;
    const int pcol = blockIdx.y * 32 + wave * 16 + l15;   // 0..63
    const bool pv  = pcol < W_;
    const ushort_t* rtn = rt + (size_t)n * HW * 256;

    float4v acc[2];
    acc[0] = (float4v)(0.f);
    acc[1] = (float4v)(0.f);

    for (int kk = 0; kk < KK; ++kk) {
        int ky = kk / 3 - 1, kx = kk % 3 - 1;
        int hy = h + ky;
        if (hy < 0 || hy >= H_) continue;          // wave-uniform
        int xr = pcol + kx;
        bool lv = pv && (xr >= 0) && (xr < W_);
        int xcc = min(max(xr, 0), W_ - 1);
        const ushort_t* brow = rtn + (size_t)(hy * W_ + xcc) * 256 + quad * 8;
#pragma unroll
        for (int c0 = 0; c0 < 256; c0 += 32) {
            short8 bf = *(const short8*)(brow + c0);
            if (!lv) bf = (short8)0;
#pragma unroll
            for (int mt = 0; mt < 2; ++mt) {
                short8 af = *(const short8*)&wofp[(size_t)(kk * 32 + mt * 16 + l15) * 256 +
                                                  c0 + quad * 8];
                acc[mt] = __builtin_amdgcn_mfma_f32_16x16x32_bf16(af, bf, acc[mt], 0, 0, 0);
            }
        }
    }

    if (pv) {
#pragma unroll
        for (int mt = 0; mt < 2; ++mt)
#pragma unroll
            for (int rr = 0; rr < 4; ++rr) {
                int m = mt * 16 + quad * 4 + rr;
                if (m < OFFC)
                    off[((size_t)n * OFFC + m) * HW + h * W_ + pcol] =
                        acc[mt][rr] + b_off[m];
            }
    }
}

// ---------------------------------------------------------------------------
// deform conv: r2t[p][o] = relu(b2[o] + sum_{k,c} sample(r_t,off)[p][k][c] w2[o][c][k])
// Fully fused, global-fed, no LDS, no barriers. A-fragments built in registers
// from 4 bilinear-corner 16B loads (NHWC makes corners contiguous in c).
// Block 128 thr = 2 waves; wave: M=16 p, N=128 o. Grid (98 p-tiles, 2 o, 4 n).
// ---------------------------------------------------------------------------
__global__ void __launch_bounds__(128, 2) deform_kernel(
    const ushort_t* __restrict__ rt, const float* __restrict__ off,
    const ushort_t* __restrict__ w2b, const float* __restrict__ b2,
    ushort_t* __restrict__ r2t)
{
    const int tid  = threadIdx.x;
    const int wave = tid >> 6;
    const int lane = tid & 63;
    const int l15  = lane & 15;
    const int quad = lane >> 4;
    const int n     = blockIdx.z;
    const int oBase = blockIdx.y * 128;
    const int p_in  = blockIdx.x * 32 + wave * 16 + l15;   // [0, 3136)
    const int h = p_in / W_;
    const int w = p_in - h * W_;
    const ushort_t* rtn = rt + (size_t)n * HW * 256;
    const float* offn   = off + (size_t)n * OFFC * HW;

    float4v acc[8];
#pragma unroll
    for (int j = 0; j < 8; ++j) acc[j] = (float4v)(0.f);

    for (int kk = 0; kk < KK; ++kk) {
        float dy = offn[(size_t)(2 * kk) * HW + p_in];
        float dx = offn[(size_t)(2 * kk + 1) * HW + p_in];
        float ys = (float)(h + kk / 3 - 1) + dy;
        float xs = (float)(w + kk % 3 - 1) + dx;
        float y0f = floorf(ys), x0f = floorf(xs);
        int y0 = (int)y0f, x0 = (int)x0f;
        float wy1 = ys - y0f, wy0 = 1.f - wy1;
        float wx1 = xs - x0f, wx0 = 1.f - wx1;

        float wc[4];
        const ushort_t* cb[4];
#pragma unroll
        for (int u = 0; u < 2; ++u)
#pragma unroll
            for (int v = 0; v < 2; ++v) {
                int yy = y0 + u, xx = x0 + v;
                bool valid = (yy >= 0) && (yy < H_) && (xx >= 0) && (xx < W_);
                wc[u * 2 + v] = valid ? (u ? wy1 : wy0) * (v ? wx1 : wx0) : 0.f;
                int yc = min(max(yy, 0), H_ - 1);
                int xc = min(max(xx, 0), W_ - 1);
                cb[u * 2 + v] = rtn + (size_t)(yc * W_ + xc) * 256 + quad * 8;
            }

#pragma unroll 2
        for (int c0 = 0; c0 < 256; c0 += 32) {
            uint4v cw[4];
#pragma unroll
            for (int j4 = 0; j4 < 4; ++j4)
                cw[j4] = *(const uint4v*)(cb[j4] + c0);
            short8 af;
#pragma unroll
            for (int j = 0; j < 8; ++j) {
                int word = j >> 1;
                float sv = 0.f;
#pragma unroll
                for (int j4 = 0; j4 < 4; ++j4) {
                    unsigned int u = cw[j4][word];
                    float vf = __uint_as_float((j & 1) ? (u & 0xffff0000u)
                                                       : (u << 16));
                    sv = fmaf(wc[j4], vf, sv);
                }
                af[j] = (short)bf16_rne(sv);
            }
#pragma unroll
            for (int nt = 0; nt < 8; ++nt) {
                short8 bf = *(const short8*)&w2b[(size_t)(oBase + nt * 16 + l15) * 2304 +
                                                 kk * 256 + c0 + quad * 8];
                acc[nt] = __builtin_amdgcn_mfma_f32_16x16x32_bf16(af, bf, acc[nt], 0, 0, 0);
            }
        }
    }

#pragma unroll
    for (int rr = 0; rr < 4; ++rr) {
        int p_row = blockIdx.x * 32 + wave * 16 + quad * 4 + rr;
#pragma unroll
        for (int nt = 0; nt < 8; ++nt) {
            int o = oBase + nt * 16 + l15;
            float v = fmaxf(acc[nt][rr] + b2[o], 0.f);
            r2t[((size_t)n * HW + p_row) * 256 + o] = bf16_rne(v);
        }
    }
}

// ---------------------------------------------------------------------------
// conv3: out = relu(x + w3 . r2 + b3), NCHW fp32 out.
// A = w3p (rows=m), B = r2t direct from global NHWC. No LDS, no barriers.
// Block 256 thr = 4 waves; M-tile 256 (wave 64 m), N = 64 p.
// Grid (196 p-tiles, 4 m-blocks).
// ---------------------------------------------------------------------------
__global__ void __launch_bounds__(256, 4) conv3_kernel(
    const ushort_t* __restrict__ w3p, const ushort_t* __restrict__ r2t,
    const float* __restrict__ b3, const float* __restrict__ x,
    float* __restrict__ out)
{
    const int tid  = threadIdx.x;
    const int wave = tid >> 6;
    const int lane = tid & 63;
    const int l15  = lane & 15;
    const int quad = lane >> 4;
    const int pBase = blockIdx.x * 64;      // global position
    const int n     = pBase / HW;
    const int p_in  = pBase % HW;
    const int mBase = blockIdx.y * 256 + wave * 64;

    float4v acc[4][4];
#pragma unroll
    for (int i = 0; i < 4; ++i)
#pragma unroll
        for (int j = 0; j < 4; ++j) acc[i][j] = (float4v)(0.f);

#pragma unroll
    for (int c0 = 0; c0 < 256; c0 += 32) {
        short8 bf[4];
#pragma unroll
        for (int nt = 0; nt < 4; ++nt)
            bf[nt] = *(const short8*)&r2t[(size_t)(pBase + nt * 16 + l15) * 256 +
                                          c0 + quad * 8];
#pragma unroll
        for (int mt = 0; mt < 4; ++mt) {
            short8 af = *(const short8*)&w3p[(size_t)(mBase + mt * 16 + l15) * 256 +
                                             c0 + quad * 8];
#pragma unroll
            for (int nt = 0; nt < 4; ++nt)
                acc[mt][nt] = __builtin_amdgcn_mfma_f32_16x16x32_bf16(
                    af, bf[nt], acc[mt][nt], 0, 0, 0);
        }
    }

#pragma unroll
    for (int mt = 0; mt < 4; ++mt)
#pragma unroll
        for (int rr = 0; rr < 4; ++rr) {
            int row = mBase + mt * 16 + quad * 4 + rr;
            float bv = b3[row];
#pragma unroll
            for (int nt = 0; nt < 4; ++nt) {
                int col = p_in + nt * 16 + l15;
                size_t idx = ((size_t)n * CIN + row) * HW + col;
                out[idx] = fmaxf(acc[mt][nt][rr] + bv + x[idx], 0.f);
            }
        }
}

// ---------------------------------------------------------------------------
// kernel_launch
// ---------------------------------------------------------------------------
extern "C" void kernel_launch(void* const* d_in, const int* in_sizes, int n_in,
                              void* d_out, int out_size, void* d_ws, size_t ws_size,
                              hipStream_t stream)
{
    const float* x     = (const float*)d_in[0];
    const float* w1    = (const float*)d_in[1];
    const float* b1    = (const float*)d_in[2];
    const float* w_off = (const float*)d_in[3];
    const float* b_off = (const float*)d_in[4];
    const float* w2    = (const float*)d_in[5];
    const float* b2    = (const float*)d_in[6];
    const float* w3    = (const float*)d_in[7];
    const float* b3    = (const float*)d_in[8];
    float* out = (float*)d_out;

    ushort_t* rt   = (ushort_t*)d_ws;                 // 3,211,264 ush (NHWC bf16)
    ushort_t* r2t  = rt + (size_t)PTOT * 256;         // 3,211,264 ush
    float*    offb = (float*)(r2t + (size_t)PTOT * 256); // 225,792 f
    ushort_t* w1p  = (ushort_t*)(offb + (size_t)N_ * OFFC * HW); // 262,144
    ushort_t* w2b  = w1p + (size_t)256 * 1024;        // 589,824
    ushort_t* w3p  = w2b + (size_t)256 * 2304;        // 262,144
    ushort_t* wofp = w3p + (size_t)1024 * 256;        //  73,728
    // total ~16.1 MB

    // 1) pack weights (all single-plane bf16)
    {
        int total = 256 * 1024 + 256 * 2304 + 1024 * 256 + 9 * 32 * 256;
        pack_weights_kernel<<<(total + 255) / 256, 256, 0, stream>>>(
            w1, w2, w3, w_off, w1p, w2b, w3p, wofp);
    }
    // 2) r_t = relu(w1 . x + b1), NHWC bf16
    {
        dim3 grid(PTOT / 64, 2);
        conv1_kernel<<<grid, 256, 0, stream>>>(x, w1p, b1, rt);
    }
    // 3) off = conv3x3(r_t, w_off) + b_off
    {
        dim3 grid(H_, 2, N_);
        offset_kernel<<<grid, 128, 0, stream>>>(rt, wofp, b_off, offb);
    }
    // 4) r2t = relu(deform(r_t, off) . w2 + b2), NHWC bf16
    {
        dim3 grid(HW / 32, 2, N_);
        deform_kernel<<<grid, 128, 0, stream>>>(rt, offb, w2b, b2, r2t);
    }
    // 5) out = relu(x + w3 . r2 + b3), NCHW fp32
    {
        dim3 grid(PTOT / 64, 4);
        conv3_kernel<<<grid, 256, 0, stream>>>(w3p, r2t, b3, x, out);
    }
}